// Round 16
// baseline (109.557 us; speedup 1.0000x reference)
//
#include <hip/hip_runtime.h>

#define INPUT_SIZE 128
#define OUTPUT_SIZE 128
#define HIDDEN 8
#define BATCH 1024

#define ICH 32                   // i-chunks (blockIdx.y) -> 4096 blocks
#define IPC (INPUT_SIZE / ICH)   // 4 i's per chunk
#define TPB 128                  // threads per block (2 waves)
#define BPT 8                    // batch elements per thread
#define SLOT 60                  // dwords: w1h2@0 b1h2@4 b2@8 w3@16 b3@24 pad W2h@28..59

typedef __fp16 half2v __attribute__((ext_vector_type(2)));
typedef unsigned int u4v __attribute__((ext_vector_type(4)));

#if defined(__has_builtin)
#if __has_builtin(__builtin_amdgcn_fdot2)
#define HAS_FDOT2 1
#endif
#endif
#ifndef HAS_FDOT2
#define HAS_FDOT2 0
#endif

static __device__ __forceinline__ half2v bch2(unsigned int u) {
    return __builtin_bit_cast(half2v, u);
}
static __device__ __forceinline__ unsigned int pk(float a, float b) {
    return __builtin_bit_cast(unsigned int, __builtin_amdgcn_cvt_pkrtz(a, b));
}

// ---------------------------------------------------------------------------
// Transpose x [B,I] -> xT [I,B]. grid (4,32), block (32,8).
// ---------------------------------------------------------------------------
__global__ void transpose_x_kernel(const float* __restrict__ x,
                                   float* __restrict__ xT) {
    __shared__ float tile[32][33];
    const int i0 = blockIdx.x * 32;
    const int b0 = blockIdx.y * 32;
    const int tx = threadIdx.x;
    const int ty = threadIdx.y;
#pragma unroll
    for (int r = ty; r < 32; r += 8)
        tile[r][tx] = x[(b0 + r) * INPUT_SIZE + (i0 + tx)];
    __syncthreads();
#pragma unroll
    for (int r = ty; r < 32; r += 8)
        xT[(i0 + r) * BATCH + (b0 + tx)] = tile[tx][r];
}

// ---------------------------------------------------------------------------
// Main kernel. block=(o,ic). Staging converts fp32 weights -> f16 (W1,b1,W2)
// in registers and writes LDS slots (prep merged away). Per i, ONE asm block
// performs all 15 ds_reads + s_waitcnt: weights exist only as asm outputs, so
// the compiler CANNOT re-materialize the loads per batch-chain (the ~70
// inst/eval fat every source-level variant exhibited). Compute: packed-f16 L1,
// h-major fused L2+L3 (fdot2), partials epilogue.
// ---------------------------------------------------------------------------
template <bool PARTIALS>
__global__ __launch_bounds__(TPB, 3)
void mlpkan_kernel(const float* __restrict__ xT,
                   const float* __restrict__ W1, const float* __restrict__ b1,
                   const float* __restrict__ W2, const float* __restrict__ b2,
                   const float* __restrict__ W3, const float* __restrict__ b3,
                   float* __restrict__ partials, float* __restrict__ out) {
    __shared__ __attribute__((aligned(16))) float wlds[IPC * SLOT];

    const int o   = blockIdx.x;
    const int ic  = blockIdx.y;
    const int tid = threadIdx.x;

    // ---- stage + convert weights: 16 threads per i-slot ----
    {
        const int ii  = tid >> 4;
        const int idx = tid & 15;
        if (ii < IPC) {
            const int n = (ic * IPC + ii) * OUTPUT_SIZE + o;
            float* d = &wlds[ii * SLOT];
            if (idx == 0) {                     // W1 8f -> 4 h2-dwords @0
                const float4 a = *(const float4*)(W1 + (size_t)n * 8);
                const float4 c = *(const float4*)(W1 + (size_t)n * 8 + 4);
                u4v p = {pk(a.x, a.y), pk(a.z, a.w), pk(c.x, c.y), pk(c.z, c.w)};
                *(u4v*)(d + 0) = p;
            } else if (idx == 1) {              // b1 8f -> 4 h2-dwords @4
                const float4 a = *(const float4*)(b1 + (size_t)n * 8);
                const float4 c = *(const float4*)(b1 + (size_t)n * 8 + 4);
                u4v p = {pk(a.x, a.y), pk(a.z, a.w), pk(c.x, c.y), pk(c.z, c.w)};
                *(u4v*)(d + 4) = p;
            } else if (idx == 2) {
                *(float4*)(d + 8)  = *(const float4*)(b2 + (size_t)n * 8);
            } else if (idx == 3) {
                *(float4*)(d + 12) = *(const float4*)(b2 + (size_t)n * 8 + 4);
            } else if (idx == 4) {
                *(float4*)(d + 16) = *(const float4*)(W3 + (size_t)n * 8);
            } else if (idx == 5) {
                *(float4*)(d + 20) = *(const float4*)(W3 + (size_t)n * 8 + 4);
            } else if (idx == 6) {
                d[24] = b3[n];
            } else if (idx >= 8) {              // W2 row (idx-8): 8f -> 4 dwords
                const int h = idx - 8;
                const float4 a = *(const float4*)(W2 + (size_t)n * 64 + h * 8);
                const float4 c = *(const float4*)(W2 + (size_t)n * 64 + h * 8 + 4);
                u4v p = {pk(a.x, a.y), pk(a.z, a.w), pk(c.x, c.y), pk(c.z, c.w)};
                *(u4v*)(d + 28 + 4 * h) = p;
            }
        }
    }
    __syncthreads();

    float acc[BPT];
#pragma unroll
    for (int j = 0; j < BPT; ++j) acc[j] = 0.0f;

    const unsigned base_off = (unsigned)(size_t)(&wlds[0]);

#pragma unroll 1
    for (int ii = 0; ii < IPC; ++ii) {
        const int i = ic * IPC + ii;

        const float4 sA = *(const float4*)(xT + (size_t)i * BATCH + 4 * tid);
        const float4 sB = *(const float4*)(xT + (size_t)i * BATCH + 512 + 4 * tid);
        const float sjs[BPT] = {sA.x, sA.y, sA.z, sA.w, sB.x, sB.y, sB.z, sB.w};

        // ---- ONE asm block: all weight ds_reads + waitcnt ----
        u4v w1q, b1q, w2q0, w2q1, w2q2, w2q3, w2q4, w2q5, w2q6, w2q7;
        float4 b2qa, b2qb, w3qa, w3qb;
        float b3r;
        const unsigned lds_off = base_off + (unsigned)(ii * (SLOT * 4));
        asm volatile(
            "ds_read_b128 %0, %15 offset:0\n\t"
            "ds_read_b128 %1, %15 offset:16\n\t"
            "ds_read_b128 %2, %15 offset:32\n\t"
            "ds_read_b128 %3, %15 offset:48\n\t"
            "ds_read_b128 %4, %15 offset:64\n\t"
            "ds_read_b128 %5, %15 offset:80\n\t"
            "ds_read_b32  %6, %15 offset:96\n\t"
            "ds_read_b128 %7, %15 offset:112\n\t"
            "ds_read_b128 %8, %15 offset:128\n\t"
            "ds_read_b128 %9, %15 offset:144\n\t"
            "ds_read_b128 %10, %15 offset:160\n\t"
            "ds_read_b128 %11, %15 offset:176\n\t"
            "ds_read_b128 %12, %15 offset:192\n\t"
            "ds_read_b128 %13, %15 offset:208\n\t"
            "ds_read_b128 %14, %15 offset:224\n\t"
            "s_waitcnt lgkmcnt(0)"
            : "=&v"(w1q), "=&v"(b1q), "=&v"(b2qa), "=&v"(b2qb),
              "=&v"(w3qa), "=&v"(w3qb), "=&v"(b3r),
              "=&v"(w2q0), "=&v"(w2q1), "=&v"(w2q2), "=&v"(w2q3),
              "=&v"(w2q4), "=&v"(w2q5), "=&v"(w2q6), "=&v"(w2q7)
            : "v"(lds_off)
            : "memory");

        const half2v zero2 = {(__fp16)0.0f, (__fp16)0.0f};

        // ---------------- layer 1 (packed f16) ----------------
        half2v h1p[BPT][4];
#pragma unroll
        for (int j = 0; j < BPT; ++j) {
            const half2v xx = __builtin_amdgcn_cvt_pkrtz(sjs[j], sjs[j]);
#pragma unroll
            for (int q = 0; q < 4; ++q) {
                const half2v v = bch2(w1q[q]) * xx + bch2(b1q[q]);   // v_pk_fma_f16
                h1p[j][q] = __builtin_elementwise_max(v, zero2);     // v_pk_max_f16
            }
        }

        // ---------------- layers 2+3 fused (h-major) ----------------
        float v3[BPT];
#pragma unroll
        for (int j = 0; j < BPT; ++j) v3[j] = 0.0f;

#if HAS_FDOT2
#define ROWDOT(t, RQ, j) \
        t = __builtin_amdgcn_fdot2(bch2(RQ[0]), h1p[j][0], t, false); \
        t = __builtin_amdgcn_fdot2(bch2(RQ[1]), h1p[j][1], t, false); \
        t = __builtin_amdgcn_fdot2(bch2(RQ[2]), h1p[j][2], t, false); \
        t = __builtin_amdgcn_fdot2(bch2(RQ[3]), h1p[j][3], t, false);
#else
#define ROWDOT(t, RQ, j) { \
        const half2v r0_ = bch2(RQ[0]), r1_ = bch2(RQ[1]); \
        const half2v r2_ = bch2(RQ[2]), r3_ = bch2(RQ[3]); \
        t = fmaf((float)r0_[0], (float)h1p[j][0][0], t); \
        t = fmaf((float)r0_[1], (float)h1p[j][0][1], t); \
        t = fmaf((float)r1_[0], (float)h1p[j][1][0], t); \
        t = fmaf((float)r1_[1], (float)h1p[j][1][1], t); \
        t = fmaf((float)r2_[0], (float)h1p[j][2][0], t); \
        t = fmaf((float)r2_[1], (float)h1p[j][2][1], t); \
        t = fmaf((float)r3_[0], (float)h1p[j][3][0], t); \
        t = fmaf((float)r3_[1], (float)h1p[j][3][1], t); }
#endif

#define L23(h, RQ) { \
        const float b2h_ = (h < 4) ? b2qa[h] : b2qb[(h) - 4]; \
        const float w3h_ = (h < 4) ? w3qa[h] : w3qb[(h) - 4]; \
        _Pragma("unroll") \
        for (int j = 0; j < BPT; ++j) { \
            float t = b2h_; \
            ROWDOT(t, RQ, j); \
            v3[j] = fmaf(w3h_, fmaxf(t, 0.0f), v3[j]); \
        } }

        L23(0, w2q0) L23(1, w2q1) L23(2, w2q2) L23(3, w2q3)
        L23(4, w2q4) L23(5, w2q5) L23(6, w2q6) L23(7, w2q7)
#undef L23
#undef ROWDOT

#pragma unroll
        for (int j = 0; j < BPT; ++j)
            acc[j] += v3[j] + b3r;
    }

    if (PARTIALS) {
        float* base = partials + ((size_t)ic * OUTPUT_SIZE + o) * BATCH;
        float4 pa = {acc[0], acc[1], acc[2], acc[3]};
        float4 pb = {acc[4], acc[5], acc[6], acc[7]};
        *(float4*)(base + 4 * tid)       = pa;
        *(float4*)(base + 512 + 4 * tid) = pb;
    } else {
#pragma unroll
        for (int j = 0; j < BPT; ++j) {
            const int b = (j < 4) ? (4 * tid + j) : (512 + 4 * tid + (j - 4));
            atomicAdd(&out[(size_t)b * OUTPUT_SIZE + o], acc[j]);
        }
    }
}

// ---------------------------------------------------------------------------
// Reduce ICH partials [ic][o][b] -> out [b][o] with LDS transpose.
// ---------------------------------------------------------------------------
__global__ void reduce_kernel(const float* __restrict__ partials,
                              float* __restrict__ out) {
    __shared__ float tile[32][33];
    const int o0 = blockIdx.x * 32;
    const int b0 = blockIdx.y * 32;
    const int tx = threadIdx.x;
    const int ty = threadIdx.y;
#pragma unroll
    for (int r = ty; r < 32; r += 16) {
        float v = 0.0f;
#pragma unroll
        for (int icc = 0; icc < ICH; ++icc)
            v += partials[((size_t)icc * OUTPUT_SIZE + o0 + r) * BATCH + b0 + tx];
        tile[r][tx] = v;
    }
    __syncthreads();
#pragma unroll
    for (int r = ty; r < 32; r += 16)
        out[(size_t)(b0 + r) * OUTPUT_SIZE + o0 + tx] = tile[tx][r];
}

// ---------------------------------------------------------------------------
// Fallback (ws too small): naive fp32 path, direct full-sum store.
// ---------------------------------------------------------------------------
__global__ __launch_bounds__(256, 2)
void mlpkan_naive(const float* __restrict__ x,
                  const float* __restrict__ W1, const float* __restrict__ b1,
                  const float* __restrict__ W2, const float* __restrict__ b2,
                  const float* __restrict__ W3, const float* __restrict__ b3,
                  float* __restrict__ out) {
    const int o = blockIdx.x;
    const int b = blockIdx.y * 256 + threadIdx.x;
    float acc = 0.0f;
    for (int i = 0; i < INPUT_SIZE; ++i) {
        const int n = i * OUTPUT_SIZE + o;
        const float s = x[b * INPUT_SIZE + i];
        float h1[8], h2[8];
#pragma unroll
        for (int k = 0; k < 8; ++k)
            h1[k] = fmaxf(fmaf(W1[(size_t)n * 8 + k], s, b1[(size_t)n * 8 + k]), 0.0f);
#pragma unroll
        for (int h = 0; h < 8; ++h) {
            float v = b2[(size_t)n * 8 + h];
#pragma unroll
            for (int k = 0; k < 8; ++k)
                v = fmaf(W2[(size_t)n * 64 + h * 8 + k], h1[k], v);
            h2[h] = fmaxf(v, 0.0f);
        }
        float v = b3[n];
#pragma unroll
        for (int k = 0; k < 8; ++k)
            v = fmaf(W3[(size_t)n * 8 + k], h2[k], v);
        acc += v;
    }
    out[(size_t)b * OUTPUT_SIZE + o] = acc;
}

extern "C" void kernel_launch(void* const* d_in, const int* in_sizes, int n_in,
                              void* d_out, int out_size, void* d_ws, size_t ws_size,
                              hipStream_t stream) {
    const float* x  = (const float*)d_in[0];
    const float* W1 = (const float*)d_in[1];
    const float* b1 = (const float*)d_in[2];
    const float* W2 = (const float*)d_in[3];
    const float* b2 = (const float*)d_in[4];
    const float* W3 = (const float*)d_in[5];
    const float* b3 = (const float*)d_in[6];
    float* out = (float*)d_out;

    const size_t xt_elems   = (size_t)INPUT_SIZE * BATCH;               // 128K f
    const size_t part_elems = (size_t)ICH * OUTPUT_SIZE * BATCH;        // 4M f
    const size_t need_bytes = (xt_elems + part_elems) * sizeof(float);  // ~16.5MB

    if (ws_size >= need_bytes) {
        float* xT       = (float*)d_ws;
        float* partials = xT + xt_elems;

        transpose_x_kernel<<<dim3(4, 32), dim3(32, 8), 0, stream>>>(x, xT);
        mlpkan_kernel<true><<<dim3(OUTPUT_SIZE, ICH), TPB, 0, stream>>>(
            xT, W1, b1, W2, b2, W3, b3, partials, out);
        reduce_kernel<<<dim3(4, 32), dim3(32, 16), 0, stream>>>(partials, out);
    } else {
        mlpkan_naive<<<dim3(OUTPUT_SIZE, BATCH / 256), 256, 0, stream>>>(
            x, W1, b1, W2, b2, W3, b3, out);
    }
}

// Round 17
// 107.436 us; speedup vs baseline: 1.0197x; 1.0197x over previous
//
#include <hip/hip_runtime.h>

#define INPUT_SIZE 128
#define OUTPUT_SIZE 128
#define HIDDEN 8
#define BATCH 1024

#define ICH 8                    // i-chunks -> grid 128x8 = 1024 blocks
#define IPC (INPUT_SIZE / ICH)   // 16 i's per chunk
#define TPB 256                  // threads per block (4 waves) -> 16 waves/CU
#define BPT 4                    // batch elems per thread (256*4 = 1024)
#define SLOT 76                  // dwords: w1h2@0 b1h2@4 b3@8 pad@9 rows@12+8h {W2row4,b2h,w3h,pad2}

typedef __fp16 half2v __attribute__((ext_vector_type(2)));
typedef unsigned int u4v __attribute__((ext_vector_type(4)));

#if defined(__has_builtin)
#if __has_builtin(__builtin_amdgcn_fdot2)
#define HAS_FDOT2 1
#endif
#endif
#ifndef HAS_FDOT2
#define HAS_FDOT2 0
#endif

static __device__ __forceinline__ half2v bch2(unsigned int u) {
    return __builtin_bit_cast(half2v, u);
}
static __device__ __forceinline__ unsigned int pk(float a, float b) {
    return __builtin_bit_cast(unsigned int, __builtin_amdgcn_cvt_pkrtz(a, b));
}

// ---------------------------------------------------------------------------
// Transpose x [B,I] -> xT [I,B]. grid (4,32), block (32,8).
// ---------------------------------------------------------------------------
__global__ void transpose_x_kernel(const float* __restrict__ x,
                                   float* __restrict__ xT) {
    __shared__ float tile[32][33];
    const int i0 = blockIdx.x * 32;
    const int b0 = blockIdx.y * 32;
    const int tx = threadIdx.x;
    const int ty = threadIdx.y;
#pragma unroll
    for (int r = ty; r < 32; r += 8)
        tile[r][tx] = x[(b0 + r) * INPUT_SIZE + (i0 + tx)];
    __syncthreads();
#pragma unroll
    for (int r = ty; r < 32; r += 8)
        xT[(i0 + r) * BATCH + (b0 + tx)] = tile[tx][r];
}

// ---------------------------------------------------------------------------
// Main kernel. block=(o,ic); 1024 blocks x 4 waves = 16 waves/CU (round-4's
// occupancy regime, the only one that measured 86.7% VALUBusy) combined with
// the f16 h-major instruction mix (~68 inst/eval vs round 4's 134).
// Staging converts fp32->f16 in registers (no prep kernel for weights).
// BPT=4 bounds worst-case weight re-read fat to +13%.
// ---------------------------------------------------------------------------
template <bool PARTIALS>
__global__ __launch_bounds__(TPB, 4)
void mlpkan_kernel(const float* __restrict__ xT,
                   const float* __restrict__ W1, const float* __restrict__ b1,
                   const float* __restrict__ W2, const float* __restrict__ b2,
                   const float* __restrict__ W3, const float* __restrict__ b3,
                   float* __restrict__ partials, float* __restrict__ out) {
    __shared__ __attribute__((aligned(16))) float wlds[IPC * SLOT];

    const int o   = blockIdx.x;
    const int ic  = blockIdx.y;
    const int tid = threadIdx.x;

    // ---- stage + convert weights: 16 threads per i-slot, 16 slots ----
    {
        const int ii  = tid >> 4;          // 0..15
        const int idx = tid & 15;
        const int n   = (ic * IPC + ii) * OUTPUT_SIZE + o;
        float* d = &wlds[ii * SLOT];
        if (idx == 0) {                    // W1 8f -> 4 h2-dwords @0
            const float4 a = *(const float4*)(W1 + (size_t)n * 8);
            const float4 c = *(const float4*)(W1 + (size_t)n * 8 + 4);
            u4v p = {pk(a.x, a.y), pk(a.z, a.w), pk(c.x, c.y), pk(c.z, c.w)};
            *(u4v*)(d + 0) = p;
        } else if (idx == 1) {             // b1 8f -> 4 h2-dwords @4
            const float4 a = *(const float4*)(b1 + (size_t)n * 8);
            const float4 c = *(const float4*)(b1 + (size_t)n * 8 + 4);
            u4v p = {pk(a.x, a.y), pk(a.z, a.w), pk(c.x, c.y), pk(c.z, c.w)};
            *(u4v*)(d + 4) = p;
        } else if (idx == 2) {
            d[8] = b3[n];
        } else if (idx >= 8) {             // row h: {W2row f16x8, b2h, w3h}
            const int h = idx - 8;
            const float4 a = *(const float4*)(W2 + (size_t)n * 64 + h * 8);
            const float4 c = *(const float4*)(W2 + (size_t)n * 64 + h * 8 + 4);
            u4v p = {pk(a.x, a.y), pk(a.z, a.w), pk(c.x, c.y), pk(c.z, c.w)};
            *(u4v*)(d + 12 + 8 * h) = p;
            d[12 + 8 * h + 4] = b2[(size_t)n * 8 + h];
            d[12 + 8 * h + 5] = W3[(size_t)n * 8 + h];
        }
    }
    __syncthreads();

    float acc[BPT];
#pragma unroll
    for (int j = 0; j < BPT; ++j) acc[j] = 0.0f;

#pragma unroll 1
    for (int ii = 0; ii < IPC; ++ii) {
        const int i = ic * IPC + ii;
        const float* w = &wlds[ii * SLOT];

        // x: one coalesced float4 (b = 4t..4t+3)
        const float4 sv = *(const float4*)(xT + (size_t)i * BATCH + 4 * tid);
        const float sjs[BPT] = {sv.x, sv.y, sv.z, sv.w};

        // ---------------- layer 1 (packed f16) ----------------
        const u4v w1q = *(const u4v*)(w + 0);
        const u4v b1q = *(const u4v*)(w + 4);
        const half2v zero2 = {(__fp16)0.0f, (__fp16)0.0f};

        half2v h1p[BPT][4];
#pragma unroll
        for (int j = 0; j < BPT; ++j) {
            const half2v xx = __builtin_amdgcn_cvt_pkrtz(sjs[j], sjs[j]);
#pragma unroll
            for (int q = 0; q < 4; ++q) {
                const half2v v = bch2(w1q[q]) * xx + bch2(b1q[q]);   // v_pk_fma_f16
                h1p[j][q] = __builtin_elementwise_max(v, zero2);     // v_pk_max_f16
            }
        }

        // ---------------- layers 2+3 fused (h-major) ----------------
        float v3[BPT];
#pragma unroll
        for (int j = 0; j < BPT; ++j) v3[j] = 0.0f;

#pragma unroll
        for (int h = 0; h < HIDDEN; ++h) {
            const u4v    row = *(const u4v*)(w + 12 + 8 * h);     // ds_read_b128
            const float2 bw  = *(const float2*)(w + 12 + 8 * h + 4); // ds_read_b64
            const float b2h = bw.x;
            const float w3h = bw.y;
#pragma unroll
            for (int j = 0; j < BPT; ++j) {
#if HAS_FDOT2
                float t = b2h;
                t = __builtin_amdgcn_fdot2(bch2(row[0]), h1p[j][0], t, false);
                t = __builtin_amdgcn_fdot2(bch2(row[1]), h1p[j][1], t, false);
                t = __builtin_amdgcn_fdot2(bch2(row[2]), h1p[j][2], t, false);
                t = __builtin_amdgcn_fdot2(bch2(row[3]), h1p[j][3], t, false);
#else
                float t = b2h;
                {
                    const half2v r0 = bch2(row[0]), r1 = bch2(row[1]);
                    const half2v r2 = bch2(row[2]), r3 = bch2(row[3]);
                    t = fmaf((float)r0[0], (float)h1p[j][0][0], t);
                    t = fmaf((float)r0[1], (float)h1p[j][0][1], t);
                    t = fmaf((float)r1[0], (float)h1p[j][1][0], t);
                    t = fmaf((float)r1[1], (float)h1p[j][1][1], t);
                    t = fmaf((float)r2[0], (float)h1p[j][2][0], t);
                    t = fmaf((float)r2[1], (float)h1p[j][2][1], t);
                    t = fmaf((float)r3[0], (float)h1p[j][3][0], t);
                    t = fmaf((float)r3[1], (float)h1p[j][3][1], t);
                }
#endif
                v3[j] = fmaf(w3h, fmaxf(t, 0.0f), v3[j]);
            }
        }

        const float b3r = w[8];
#pragma unroll
        for (int j = 0; j < BPT; ++j)
            acc[j] += v3[j] + b3r;
    }

    if (PARTIALS) {
        float* base = partials + ((size_t)ic * OUTPUT_SIZE + o) * BATCH;
        float4 pa = {acc[0], acc[1], acc[2], acc[3]};
        *(float4*)(base + 4 * tid) = pa;
    } else {
#pragma unroll
        for (int j = 0; j < BPT; ++j)
            atomicAdd(&out[(size_t)(4 * tid + j) * OUTPUT_SIZE + o], acc[j]);
    }
}

// ---------------------------------------------------------------------------
// Reduce ICH=8 partials [ic][o][b] -> out [b][o] with LDS transpose.
// ---------------------------------------------------------------------------
__global__ void reduce_kernel(const float* __restrict__ partials,
                              float* __restrict__ out) {
    __shared__ float tile[32][33];
    const int o0 = blockIdx.x * 32;
    const int b0 = blockIdx.y * 32;
    const int tx = threadIdx.x;
    const int ty = threadIdx.y;
#pragma unroll
    for (int r = ty; r < 32; r += 16) {
        float v = 0.0f;
#pragma unroll
        for (int icc = 0; icc < ICH; ++icc)
            v += partials[((size_t)icc * OUTPUT_SIZE + o0 + r) * BATCH + b0 + tx];
        tile[r][tx] = v;
    }
    __syncthreads();
#pragma unroll
    for (int r = ty; r < 32; r += 16)
        out[(size_t)(b0 + r) * OUTPUT_SIZE + o0 + tx] = tile[tx][r];
}

// ---------------------------------------------------------------------------
// Fallback (ws too small): naive fp32 path, direct full-sum store.
// ---------------------------------------------------------------------------
__global__ __launch_bounds__(256, 2)
void mlpkan_naive(const float* __restrict__ x,
                  const float* __restrict__ W1, const float* __restrict__ b1,
                  const float* __restrict__ W2, const float* __restrict__ b2,
                  const float* __restrict__ W3, const float* __restrict__ b3,
                  float* __restrict__ out) {
    const int o = blockIdx.x;
    const int b = blockIdx.y * 256 + threadIdx.x;
    float acc = 0.0f;
    for (int i = 0; i < INPUT_SIZE; ++i) {
        const int n = i * OUTPUT_SIZE + o;
        const float s = x[b * INPUT_SIZE + i];
        float h1[8], h2[8];
#pragma unroll
        for (int k = 0; k < 8; ++k)
            h1[k] = fmaxf(fmaf(W1[(size_t)n * 8 + k], s, b1[(size_t)n * 8 + k]), 0.0f);
#pragma unroll
        for (int h = 0; h < 8; ++h) {
            float v = b2[(size_t)n * 8 + h];
#pragma unroll
            for (int k = 0; k < 8; ++k)
                v = fmaf(W2[(size_t)n * 64 + h * 8 + k], h1[k], v);
            h2[h] = fmaxf(v, 0.0f);
        }
        float v = b3[n];
#pragma unroll
        for (int k = 0; k < 8; ++k)
            v = fmaf(W3[(size_t)n * 8 + k], h2[k], v);
        acc += v;
    }
    out[(size_t)b * OUTPUT_SIZE + o] = acc;
}

extern "C" void kernel_launch(void* const* d_in, const int* in_sizes, int n_in,
                              void* d_out, int out_size, void* d_ws, size_t ws_size,
                              hipStream_t stream) {
    const float* x  = (const float*)d_in[0];
    const float* W1 = (const float*)d_in[1];
    const float* b1 = (const float*)d_in[2];
    const float* W2 = (const float*)d_in[3];
    const float* b2 = (const float*)d_in[4];
    const float* W3 = (const float*)d_in[5];
    const float* b3 = (const float*)d_in[6];
    float* out = (float*)d_out;

    const size_t xt_elems   = (size_t)INPUT_SIZE * BATCH;               // 128K f
    const size_t part_elems = (size_t)ICH * OUTPUT_SIZE * BATCH;        // 1M f
    const size_t need_bytes = (xt_elems + part_elems) * sizeof(float);  // ~4.5MB

    if (ws_size >= need_bytes) {
        float* xT       = (float*)d_ws;
        float* partials = xT + xt_elems;

        transpose_x_kernel<<<dim3(4, 32), dim3(32, 8), 0, stream>>>(x, xT);
        mlpkan_kernel<true><<<dim3(OUTPUT_SIZE, ICH), TPB, 0, stream>>>(
            xT, W1, b1, W2, b2, W3, b3, partials, out);
        reduce_kernel<<<dim3(4, 32), dim3(32, 16), 0, stream>>>(partials, out);
    } else {
        mlpkan_naive<<<dim3(OUTPUT_SIZE, BATCH / 256), 256, 0, stream>>>(
            x, W1, b1, W2, b2, W3, b3, out);
    }
}